// Round 1
// baseline (175.209 us; speedup 1.0000x reference)
//
#include <hip/hip_runtime.h>
#include <hip/hip_bf16.h>
#include <stdint.h>

#define S_LEN 2048
#define EMB   1536
#define NH    12
#define HD    128
#define N3    4608
#define RMS_EPS 1e-5f
#define ATTN_SCALE 0.08838834764831845f  // 1/sqrt(128)

typedef short short8_t __attribute__((ext_vector_type(8)));
typedef float f32x4    __attribute__((ext_vector_type(4)));

typedef __attribute__((address_space(1))) const void g1_void;
typedef __attribute__((address_space(3))) void l3_void;

__device__ __forceinline__ void gload_lds16(const void* g, void* l) {
  __builtin_amdgcn_global_load_lds((g1_void*)g, (l3_void*)l, 16, 0, 0);
}

__device__ __forceinline__ short f2bf(float f) {
  union { float f; unsigned u; } v; v.f = f;
  unsigned r = (v.u + 0x7FFFu + ((v.u >> 16) & 1u)) >> 16;
  return (short)(r & 0xFFFFu);
}

// ---------------- fp32 -> bf16 elementwise ----------------
__global__ __launch_bounds__(256) void k_cvt_bf16(const float* __restrict__ in,
                                                  short* __restrict__ out, int n) {
  int i = (blockIdx.x * 256 + threadIdx.x) * 4;
  if (i + 3 < n) {
    float4 v = *(const float4*)(in + i);
    short4 o;
    o.x = f2bf(v.x); o.y = f2bf(v.y); o.z = f2bf(v.z); o.w = f2bf(v.w);
    *(short4*)(out + i) = o;
  }
}

// ---------------- (K,N) fp32 -> (N,K) bf16 transpose ----------------
__global__ __launch_bounds__(256) void k_transpose_cvt(const float* __restrict__ W,
                                                       short* __restrict__ Wt,
                                                       int K, int N) {
  __shared__ float t[32][33];
  int n0 = blockIdx.x * 32, k0 = blockIdx.y * 32;
  int tx = threadIdx.x, ty = threadIdx.y;  // block (32,8)
#pragma unroll
  for (int r = 0; r < 4; ++r) {
    int k = ty + r * 8;
    t[k][tx] = W[(size_t)(k0 + k) * N + n0 + tx];
  }
  __syncthreads();
#pragma unroll
  for (int r = 0; r < 4; ++r) {
    int j = ty + r * 8;
    Wt[(size_t)(n0 + j) * K + k0 + tx] = f2bf(t[tx][j]);
  }
}

// ---------------- V slice of qkv (fp32) -> (h, d, s) bf16 ----------------
__global__ __launch_bounds__(256) void k_transpose_v(const float* __restrict__ qkv,
                                                     short* __restrict__ vt) {
  __shared__ float t[32][33];
  int s0 = blockIdx.x * 32, d0 = blockIdx.y * 32, h = blockIdx.z;
  int tx = threadIdx.x, ty = threadIdx.y;  // block (32,8)
#pragma unroll
  for (int r = 0; r < 4; ++r) {
    int i = ty + r * 8;
    t[i][tx] = qkv[(size_t)(s0 + i) * N3 + 2 * EMB + h * HD + d0 + tx];
  }
  __syncthreads();
#pragma unroll
  for (int r = 0; r < 4; ++r) {
    int j = ty + r * 8;
    vt[((size_t)h * HD + d0 + j) * S_LEN + s0 + tx] = f2bf(t[tx][j]);
  }
}

// ---------------- bf16 GEMM: C(M,N) = A(M,K) * Bt(N,K)^T + bias, fp32 out ----------------
__global__ __launch_bounds__(256) void k_gemm_bt(const short* __restrict__ A,
                                                 const short* __restrict__ Bt,
                                                 const float* __restrict__ bias,
                                                 float* __restrict__ C,
                                                 int M, int N, int K) {
  __shared__ short lA[128 * 32];
  __shared__ short lB[128 * 32];
  const int tid = threadIdx.x;
  const int l = tid & 63, wid = tid >> 6;
  const int wr = (wid >> 1) * 64, wc = (wid & 1) * 64;
  const int bn = blockIdx.x * 128, bm = blockIdx.y * 128;
  const int lr = l & 15, lg = l >> 4, lk = lg * 8;

  f32x4 acc[4][4] = {};

  for (int kt = 0; kt < K; kt += 32) {
    __syncthreads();
#pragma unroll
    for (int it = 0; it < 2; ++it) {
      int c = it * 256 + tid;          // chunk of 8 bf16 (16B)
      int row = c >> 2, ch = c & 3;
      const short* srcA = A + (size_t)(bm + row) * K + kt + ch * 8;
      const short* srcB = Bt + (size_t)(bn + row) * K + kt + ch * 8;
      short* dA = &lA[(it * 256 + (tid & ~63)) * 8];
      short* dB = &lB[(it * 256 + (tid & ~63)) * 8];
      gload_lds16(srcA, dA);
      gload_lds16(srcB, dB);
    }
    __syncthreads();
    short8_t af[4], bfr[4];
#pragma unroll
    for (int m = 0; m < 4; ++m) af[m]  = *(const short8_t*)&lA[(wr + m * 16 + lr) * 32 + lk];
#pragma unroll
    for (int n = 0; n < 4; ++n) bfr[n] = *(const short8_t*)&lB[(wc + n * 16 + lr) * 32 + lk];
#pragma unroll
    for (int m = 0; m < 4; ++m)
#pragma unroll
      for (int n = 0; n < 4; ++n)
        acc[m][n] = __builtin_amdgcn_mfma_f32_16x16x32_bf16(af[m], bfr[n], acc[m][n], 0, 0, 0);
  }

#pragma unroll
  for (int m = 0; m < 4; ++m)
#pragma unroll
    for (int n = 0; n < 4; ++n) {
      int col = bn + wc + n * 16 + lr;
      float bv = bias[col];
#pragma unroll
      for (int r = 0; r < 4; ++r) {
        int row = bm + wr + m * 16 + lg * 4 + r;
        C[(size_t)row * N + col] = acc[m][n][r] + bv;
      }
    }
}

// ---------------- RMSNorm + RoPE on q,k -> (h,s,d) bf16 ----------------
__global__ __launch_bounds__(128) void k_rmsrope(const float* __restrict__ qkv,
                                                 const float* __restrict__ cosv,
                                                 const float* __restrict__ sinv,
                                                 const float* __restrict__ qw,
                                                 const float* __restrict__ kw,
                                                 short* __restrict__ qb,
                                                 short* __restrict__ kb) {
  int s = blockIdx.x, h = blockIdx.y, t = threadIdx.x;
  const float* base = qkv + (size_t)s * N3 + h * HD;
  float qv = base[t];
  float kv = base[EMB + t];
  float qs = qv * qv, ks = kv * kv;
#pragma unroll
  for (int off = 32; off > 0; off >>= 1) {
    qs += __shfl_xor(qs, off);
    ks += __shfl_xor(ks, off);
  }
  __shared__ float red[2][2];
  int wv = t >> 6;
  if ((t & 63) == 0) { red[wv][0] = qs; red[wv][1] = ks; }
  __syncthreads();
  qs = red[0][0] + red[1][0];
  ks = red[0][1] + red[1][1];
  float qn = qv * rsqrtf(qs * (1.0f / HD) + RMS_EPS) * qw[t];
  float kn = kv * rsqrtf(ks * (1.0f / HD) + RMS_EPS) * kw[t];
  __shared__ float sq[128], sk[128];
  sq[t] = qn; sk[t] = kn;
  __syncthreads();
  float qo, ko;
  if (t < 64) {
    float c = cosv[s * 64 + t], sn = sinv[s * 64 + t];
    qo = qn * c - sq[t + 64] * sn;
    ko = kn * c - sk[t + 64] * sn;
  } else {
    float c = cosv[s * 64 + t - 64], sn = sinv[s * 64 + t - 64];
    qo = qn * c + sq[t - 64] * sn;
    ko = kn * c + sk[t - 64] * sn;
  }
  size_t o = ((size_t)h * S_LEN + s) * HD + t;
  qb[o] = f2bf(qo);
  kb[o] = f2bf(ko);
}

// ---------------- flash attention per (head, 64-row q-tile) ----------------
__global__ __launch_bounds__(256) void k_attn(const short* __restrict__ qb,
                                              const short* __restrict__ kb,
                                              const short* __restrict__ vt,
                                              const int* __restrict__ cu, int nseg,
                                              short* __restrict__ ctx) {
  __shared__ short ldsK[64 * 128];   // [key][d], swizzled
  __shared__ short ldsV[128 * 64];   // [d][key], swizzled
  __shared__ short ldsP[4 * 16 * 64];

  const int h = blockIdx.x, qt = blockIdx.y;
  const int q0 = qt * 64;
  const int tid = threadIdx.x, l = tid & 63, w = tid >> 6;
  const int lr = l & 15, lg = l >> 4;

  int rows[4], rs[4], re[4];
  float m[4], lsum[4];
#pragma unroll
  for (int r = 0; r < 4; ++r) {
    int row = q0 + w * 16 + lg * 4 + r;
    rows[r] = row;
    int seg = 0;
    for (int i = 1; i <= nseg; ++i) if (row >= cu[i]) seg = i;
    rs[r] = (seg == 0) ? 0 : cu[seg];
    re[r] = (seg < nseg) ? cu[seg + 1] : S_LEN;
    m[r] = -INFINITY;
    lsum[r] = 0.f;
  }

  // block-uniform K range (segments are monotone in row index)
  int seg0 = 0, seg1 = 0;
  for (int i = 1; i <= nseg; ++i) {
    if (q0 >= cu[i]) seg0 = i;
    if (q0 + 63 >= cu[i]) seg1 = i;
  }
  const int ks = (seg0 == 0) ? 0 : cu[seg0];
  const int ke = (seg1 < nseg) ? cu[seg1 + 1] : S_LEN;
  const int kt0 = (ks >> 6) << 6;

  // Q fragments in registers (A-operand: row = lr, k-chunk = lg*8)
  short8_t qf[4];
  {
    int srow = q0 + w * 16 + lr;
    const short* qp = qb + ((size_t)h * S_LEN + srow) * HD;
#pragma unroll
    for (int kk = 0; kk < 4; ++kk)
      qf[kk] = *(const short8_t*)(qp + kk * 32 + lg * 8);
  }

  f32x4 cacc[8] = {};

  for (int kt = kt0; kt < ke; kt += 64) {
    __syncthreads();
    // stage K tile [64][128]
#pragma unroll
    for (int it = 0; it < 4; ++it) {
      int c = it * 256 + tid;
      int row = c >> 4, cc = c & 15;
      short8_t v = *(const short8_t*)&kb[((size_t)h * S_LEN + kt + row) * HD + cc * 8];
      int byte = row * 256 + cc * 16;
      byte ^= (row & 7) << 4;
      *(short8_t*)((char*)ldsK + byte) = v;
    }
    // stage V^T tile [128][64]
#pragma unroll
    for (int it = 0; it < 4; ++it) {
      int c = it * 256 + tid;
      int d = c >> 3, cc = c & 7;
      short8_t v = *(const short8_t*)&vt[((size_t)h * HD + d) * S_LEN + kt + cc * 8];
      int byte = d * 128 + cc * 16;
      byte ^= (d & 7) << 4;
      *(short8_t*)((char*)ldsV + byte) = v;
    }
    __syncthreads();

    // scores: S = Q K^T  (per wave: 16 rows x 64 keys)
    f32x4 sacc[4] = {};
#pragma unroll
    for (int n = 0; n < 4; ++n) {
#pragma unroll
      for (int kk = 0; kk < 4; ++kk) {
        int row = n * 16 + lr;
        int byte = row * 256 + (kk * 32 + lg * 8) * 2;
        byte ^= (row & 7) << 4;
        short8_t kf = *(const short8_t*)((const char*)ldsK + byte);
        sacc[n] = __builtin_amdgcn_mfma_f32_16x16x32_bf16(qf[kk], kf, sacc[n], 0, 0, 0);
      }
    }

    // masked online softmax
    float sv[4][4];
#pragma unroll
    for (int n = 0; n < 4; ++n) {
      int key = kt + n * 16 + lr;
#pragma unroll
      for (int r = 0; r < 4; ++r) {
        float x = sacc[n][r] * ATTN_SCALE;
        sv[n][r] = (key >= rs[r] && key < re[r]) ? x : -1e30f;
      }
    }
    float alpha[4];
#pragma unroll
    for (int r = 0; r < 4; ++r) {
      float tm = fmaxf(fmaxf(sv[0][r], sv[1][r]), fmaxf(sv[2][r], sv[3][r]));
#pragma unroll
      for (int off = 1; off < 16; off <<= 1) tm = fmaxf(tm, __shfl_xor(tm, off));
      float mn = fmaxf(m[r], tm);
      alpha[r] = __expf(m[r] - mn);
      m[r] = mn;
      float ls = 0.f;
#pragma unroll
      for (int n = 0; n < 4; ++n) {
        float p = __expf(sv[n][r] - mn);
        sv[n][r] = p;
        ls += p;
      }
#pragma unroll
      for (int off = 1; off < 16; off <<= 1) ls += __shfl_xor(ls, off);
      lsum[r] = lsum[r] * alpha[r] + ls;
    }
#pragma unroll
    for (int n = 0; n < 8; ++n)
#pragma unroll
      for (int r = 0; r < 4; ++r) cacc[n][r] *= alpha[r];

    // P -> LDS (per-wave region), swizzled
#pragma unroll
    for (int n = 0; n < 4; ++n)
#pragma unroll
      for (int r = 0; r < 4; ++r) {
        int prow = lg * 4 + r;
        int pcol = n * 16 + lr;
        int byte = prow * 128 + pcol * 2;
        byte ^= (prow & 7) << 4;
        *(short*)((char*)ldsP + w * 2048 + byte) = f2bf(sv[n][r]);
      }
    __syncthreads();

    // PV: ctx += P V   (A = P rows, B = V^T cols)
#pragma unroll
    for (int kk = 0; kk < 2; ++kk) {
      int byteP = lr * 128 + (kk * 32 + lg * 8) * 2;
      byteP ^= (lr & 7) << 4;
      short8_t pf = *(const short8_t*)((const char*)ldsP + w * 2048 + byteP);
#pragma unroll
      for (int n = 0; n < 8; ++n) {
        int d = n * 16 + lr;
        int byteV = d * 128 + (kk * 32 + lg * 8) * 2;
        byteV ^= (d & 7) << 4;
        short8_t vf = *(const short8_t*)((const char*)ldsV + byteV);
        cacc[n] = __builtin_amdgcn_mfma_f32_16x16x32_bf16(pf, vf, cacc[n], 0, 0, 0);
      }
    }
  }

  // epilogue: normalize and store ctx (s, h*d) bf16
#pragma unroll
  for (int r = 0; r < 4; ++r) {
    float inv = 1.0f / lsum[r];
#pragma unroll
    for (int n = 0; n < 8; ++n) {
      float v = cacc[n][r] * inv;
      ctx[(size_t)rows[r] * EMB + h * HD + n * 16 + lr] = f2bf(v);
    }
  }
}

extern "C" void kernel_launch(void* const* d_in, const int* in_sizes, int n_in,
                              void* d_out, int out_size, void* d_ws, size_t ws_size,
                              hipStream_t stream) {
  const float* x      = (const float*)d_in[0];
  const int*   cu     = (const int*)d_in[1];
  const float* cosv   = (const float*)d_in[2];
  const float* sinv   = (const float*)d_in[3];
  const float* w_qkv  = (const float*)d_in[4];
  const float* b_qkv  = (const float*)d_in[5];
  const float* q_norm = (const float*)d_in[6];
  const float* k_norm = (const float*)d_in[7];
  const float* w_proj = (const float*)d_in[8];
  const float* b_proj = (const float*)d_in[9];
  const int nseg = in_sizes[1] - 1;

  char* ws = (char*)d_ws;
  short* xb     = (short*)(ws);                    //  6,291,456 B
  short* wqkvT  = (short*)(ws + 6291456);          // 14,155,776 B
  short* wprojT = (short*)(ws + 20447232);         //  4,718,592 B
  float* qkv    = (float*)(ws + 25165824);         // 37,748,736 B
  short* qb     = (short*)(ws + 62914560);         //  6,291,456 B
  short* kb     = (short*)(ws + 69206016);         //  6,291,456 B
  short* vt     = (short*)(ws + 75497472);         //  6,291,456 B
  short* ctxb   = (short*)(ws + 81788928);         //  6,291,456 B (end 88,080,384)

  k_cvt_bf16<<<(S_LEN * EMB) / 1024, 256, 0, stream>>>(x, xb, S_LEN * EMB);
  k_transpose_cvt<<<dim3(N3 / 32, EMB / 32), dim3(32, 8), 0, stream>>>(w_qkv, wqkvT, EMB, N3);
  k_transpose_cvt<<<dim3(EMB / 32, EMB / 32), dim3(32, 8), 0, stream>>>(w_proj, wprojT, EMB, EMB);
  k_gemm_bt<<<dim3(N3 / 128, S_LEN / 128), 256, 0, stream>>>(xb, wqkvT, b_qkv, qkv, S_LEN, N3, EMB);
  k_rmsrope<<<dim3(S_LEN, NH), 128, 0, stream>>>(qkv, cosv, sinv, q_norm, k_norm, qb, kb);
  k_transpose_v<<<dim3(S_LEN / 32, HD / 32, NH), dim3(32, 8), 0, stream>>>(qkv, vt);
  k_attn<<<dim3(NH, S_LEN / 64), 256, 0, stream>>>(qb, kb, vt, cu, nseg, ctxb);
  k_gemm_bt<<<dim3(EMB / 128, S_LEN / 128), 256, 0, stream>>>(ctxb, wprojT, b_proj, (float*)d_out, S_LEN, EMB, EMB);
}

// Round 2
// 150.568 us; speedup vs baseline: 1.1637x; 1.1637x over previous
//
#include <hip/hip_runtime.h>
#include <hip/hip_bf16.h>
#include <stdint.h>

#define S_LEN 2048
#define EMB   1536
#define NH    12
#define HD    128
#define N3    4608
#define RMS_EPS 1e-5f
#define ATTN_SCALE 0.08838834764831845f  // 1/sqrt(128)

typedef short short8_t __attribute__((ext_vector_type(8)));
typedef float f32x4    __attribute__((ext_vector_type(4)));

typedef __attribute__((address_space(1))) const void g1_void;
typedef __attribute__((address_space(3))) void l3_void;

__device__ __forceinline__ void gload_lds16(const void* g, void* l) {
  __builtin_amdgcn_global_load_lds((g1_void*)g, (l3_void*)l, 16, 0, 0);
}

__device__ __forceinline__ short f2bf(float f) {
  union { float f; unsigned u; } v; v.f = f;
  unsigned r = (v.u + 0x7FFFu + ((v.u >> 16) & 1u)) >> 16;
  return (short)(r & 0xFFFFu);
}
__device__ __forceinline__ float bf2f(short s) {
  union { unsigned u; float f; } v; v.u = ((unsigned)(unsigned short)s) << 16;
  return v.f;
}

// ---------------- fp32 -> bf16 elementwise ----------------
__global__ __launch_bounds__(256) void k_cvt_bf16(const float* __restrict__ in,
                                                  short* __restrict__ out, int n) {
  int i = (blockIdx.x * 256 + threadIdx.x) * 4;
  if (i + 3 < n) {
    float4 v = *(const float4*)(in + i);
    short4 o;
    o.x = f2bf(v.x); o.y = f2bf(v.y); o.z = f2bf(v.z); o.w = f2bf(v.w);
    *(short4*)(out + i) = o;
  }
}

// ---------------- (K,N) fp32 -> (N,K) bf16 transpose ----------------
__global__ __launch_bounds__(256) void k_transpose_cvt(const float* __restrict__ W,
                                                       short* __restrict__ Wt,
                                                       int K, int N) {
  __shared__ float t[32][33];
  int n0 = blockIdx.x * 32, k0 = blockIdx.y * 32;
  int tx = threadIdx.x, ty = threadIdx.y;  // block (32,8)
#pragma unroll
  for (int r = 0; r < 4; ++r) {
    int k = ty + r * 8;
    t[k][tx] = W[(size_t)(k0 + k) * N + n0 + tx];
  }
  __syncthreads();
#pragma unroll
  for (int r = 0; r < 4; ++r) {
    int j = ty + r * 8;
    Wt[(size_t)(n0 + j) * K + k0 + tx] = f2bf(t[tx][j]);
  }
}

// ---------------- bf16 GEMM v2: 128x128 tile, BK=64, dbuf, 2-phase, swizzled ----------------
// C(M,N) = A(M,K) * Bt(N,K)^T + bias.  OBF: write bf16, else fp32.
template<bool OBF>
__global__ __launch_bounds__(256) void k_gemm_v2(const short* __restrict__ A,
                                                 const short* __restrict__ Bt,
                                                 const float* __restrict__ bias,
                                                 void* __restrict__ Cv,
                                                 int M, int N, int K) {
  __shared__ short lds[2][2][128 * 64];   // [buf][A/B][row*64 + k], 64 KiB
  const int tid = threadIdx.x;
  const int lane = tid & 63, wid = tid >> 6;
  const int wr = (wid >> 1) * 64, wc = (wid & 1) * 64;
  const int bn = blockIdx.x * 128, bm = blockIdx.y * 128;
  const int lr = lane & 15, lg = lane >> 4;
  const int swz = (lr & 7) << 4;

  // staging: per wave, 4 issues; each issue covers 8 rows x 128B linearly.
  // lane l writes LDS linear byte seg*1024 + l*16; we pre-swizzle the GLOBAL
  // source so that read-side byte ^ ((row&7)<<4) sees data (row, kchunk).
  const int srow = lane >> 3;                  // row within 8-row segment
  const int skc  = ((lane & 7) ^ srow) * 8;    // k offset (shorts) for this slot

  f32x4 acc[4][4] = {};
  const int nk = K >> 6;

  // prologue: stage tile 0 into buf 0
#pragma unroll
  for (int it = 0; it < 4; ++it) {
    int seg = wid * 4 + it;
    int row = seg * 8 + srow;
    gload_lds16(A  + (size_t)(bm + row) * K + skc, &lds[0][0][seg * 512]);
    gload_lds16(Bt + (size_t)(bn + row) * K + skc, &lds[0][1][seg * 512]);
  }
  __syncthreads();

  int cur = 0;
  for (int t = 0; t < nk; ++t) {
    if (t + 1 < nk) {
      const int kt = (t + 1) << 6;
#pragma unroll
      for (int it = 0; it < 4; ++it) {
        int seg = wid * 4 + it;
        int row = seg * 8 + srow;
        gload_lds16(A  + (size_t)(bm + row) * K + kt + skc, &lds[cur ^ 1][0][seg * 512]);
        gload_lds16(Bt + (size_t)(bn + row) * K + kt + skc, &lds[cur ^ 1][1][seg * 512]);
      }
    }
    const char* baseA = (const char*)&lds[cur][0][0];
    const char* baseB = (const char*)&lds[cur][1][0];
#pragma unroll
    for (int kk = 0; kk < 2; ++kk) {
      short8_t af[4], bfr[4];
#pragma unroll
      for (int m = 0; m < 4; ++m) {
        int row = wr + m * 16 + lr;
        af[m] = *(const short8_t*)(baseA + ((row * 128 + kk * 64 + lg * 16) ^ swz));
      }
#pragma unroll
      for (int n = 0; n < 4; ++n) {
        int row = wc + n * 16 + lr;
        bfr[n] = *(const short8_t*)(baseB + ((row * 128 + kk * 64 + lg * 16) ^ swz));
      }
#pragma unroll
      for (int m = 0; m < 4; ++m)
#pragma unroll
        for (int n = 0; n < 4; ++n)
          acc[m][n] = __builtin_amdgcn_mfma_f32_16x16x32_bf16(af[m], bfr[n], acc[m][n], 0, 0, 0);
    }
    __syncthreads();   // drains vmcnt(0): next buf staged & visible
    cur ^= 1;
  }

#pragma unroll
  for (int m = 0; m < 4; ++m)
#pragma unroll
    for (int n = 0; n < 4; ++n) {
      int col = bn + wc + n * 16 + lr;
      float bv = bias[col];
#pragma unroll
      for (int r = 0; r < 4; ++r) {
        int row = bm + wr + m * 16 + lg * 4 + r;
        float v = acc[m][n][r] + bv;
        if (OBF) ((short*)Cv)[(size_t)row * N + col] = f2bf(v);
        else     ((float*)Cv)[(size_t)row * N + col] = v;
      }
    }
}

// ---------------- fused RMSNorm + RoPE (q,k) + V transpose, qkv in bf16 ----------------
__global__ __launch_bounds__(256) void k_post(const short* __restrict__ qkv,
                                              const float* __restrict__ cosv,
                                              const float* __restrict__ sinv,
                                              const float* __restrict__ qw,
                                              const float* __restrict__ kw,
                                              short* __restrict__ qb,
                                              short* __restrict__ kb,
                                              short* __restrict__ vt) {
  __shared__ short ldsv[64 * 130];  // odd dword stride -> conflict-free transpose read
  const int h = blockIdx.x, s0 = blockIdx.y * 64;
  const int t = threadIdx.x;
  const int r = t >> 2, j = t & 3;   // row r (0..63), quarter j (32 d-elems each)
  const int s = s0 + r;
  const size_t rowbase = (size_t)s * N3 + h * HD;

  // stage V tile to LDS (bf16 passthrough)
  {
    const short* vp = qkv + rowbase + 2 * EMB + j * 32;
#pragma unroll
    for (int i4 = 0; i4 < 4; ++i4)
      *(short8_t*)&ldsv[r * 130 + j * 32 + i4 * 8] = *(const short8_t*)(vp + i4 * 8);
  }

  // q and k: rmsnorm (4-lane shfl reduce) + rope (pair exchange via shfl_xor 2)
#pragma unroll
  for (int qk = 0; qk < 2; ++qk) {
    const short* p = qkv + rowbase + qk * EMB + j * 32;
    const float* w = qk ? kw : qw;
    float v[32];
#pragma unroll
    for (int i4 = 0; i4 < 4; ++i4) {
      short8_t x = *(const short8_t*)(p + i4 * 8);
#pragma unroll
      for (int e = 0; e < 8; ++e) v[i4 * 8 + e] = bf2f(x[e]);
    }
    float ss = 0.f;
#pragma unroll
    for (int i = 0; i < 32; ++i) ss += v[i] * v[i];
    ss += __shfl_xor(ss, 1);
    ss += __shfl_xor(ss, 2);
    float rsq = rsqrtf(ss * (1.0f / HD) + RMS_EPS);
#pragma unroll
    for (int i = 0; i < 32; ++i) v[i] = v[i] * rsq * w[j * 32 + i];
    const float* cp = cosv + (size_t)s * 64 + (j & 1) * 32;
    const float* sp = sinv + (size_t)s * 64 + (j & 1) * 32;
    short out[32];
#pragma unroll
    for (int i = 0; i < 32; ++i) {
      float part = __shfl_xor(v[i], 2);
      float c = cp[i], sn = sp[i];
      float o = (j < 2) ? (v[i] * c - part * sn) : (v[i] * c + part * sn);
      out[i] = f2bf(o);
    }
    short* dst = (qk ? kb : qb) + ((size_t)h * S_LEN + s) * HD + j * 32;
#pragma unroll
    for (int i4 = 0; i4 < 4; ++i4) {
      short8_t o8;
#pragma unroll
      for (int e = 0; e < 8; ++e) o8[e] = out[i4 * 8 + e];
      *(short8_t*)(dst + i4 * 8) = o8;
    }
  }

  __syncthreads();
  // V transposed store: vt[h][d][s]
  const int sl = t & 63, wv = t >> 6;
#pragma unroll
  for (int it = 0; it < 32; ++it) {
    int d = it * 4 + wv;
    vt[((size_t)h * HD + d) * S_LEN + s0 + sl] = ldsv[sl * 130 + d];
  }
}

// ---------------- flash attention per (head, 64-row q-tile) ----------------
__global__ __launch_bounds__(256) void k_attn(const short* __restrict__ qb,
                                              const short* __restrict__ kb,
                                              const short* __restrict__ vt,
                                              const int* __restrict__ cu, int nseg,
                                              short* __restrict__ ctx) {
  __shared__ short ldsK[64 * 128];   // [key][d], swizzled
  __shared__ short ldsV[128 * 64];   // [d][key], swizzled
  __shared__ short ldsP[4 * 16 * 64];

  const int h = blockIdx.x, qt = blockIdx.y;
  const int q0 = qt * 64;
  const int tid = threadIdx.x, l = tid & 63, w = tid >> 6;
  const int lr = l & 15, lg = l >> 4;

  int rows[4], rs[4], re[4];
  float m[4], lsum[4];
#pragma unroll
  for (int r = 0; r < 4; ++r) {
    int row = q0 + w * 16 + lg * 4 + r;
    rows[r] = row;
    int seg = 0;
    for (int i = 1; i <= nseg; ++i) if (row >= cu[i]) seg = i;
    rs[r] = (seg == 0) ? 0 : cu[seg];
    re[r] = (seg < nseg) ? cu[seg + 1] : S_LEN;
    m[r] = -INFINITY;
    lsum[r] = 0.f;
  }

  int seg0 = 0, seg1 = 0;
  for (int i = 1; i <= nseg; ++i) {
    if (q0 >= cu[i]) seg0 = i;
    if (q0 + 63 >= cu[i]) seg1 = i;
  }
  const int ks = (seg0 == 0) ? 0 : cu[seg0];
  const int ke = (seg1 < nseg) ? cu[seg1 + 1] : S_LEN;
  const int kt0 = (ks >> 6) << 6;

  short8_t qf[4];
  {
    int srow = q0 + w * 16 + lr;
    const short* qp = qb + ((size_t)h * S_LEN + srow) * HD;
#pragma unroll
    for (int kk = 0; kk < 4; ++kk)
      qf[kk] = *(const short8_t*)(qp + kk * 32 + lg * 8);
  }

  f32x4 cacc[8] = {};

  for (int kt = kt0; kt < ke; kt += 64) {
    __syncthreads();
#pragma unroll
    for (int it = 0; it < 4; ++it) {
      int c = it * 256 + tid;
      int row = c >> 4, cc = c & 15;
      short8_t v = *(const short8_t*)&kb[((size_t)h * S_LEN + kt + row) * HD + cc * 8];
      int byte = row * 256 + cc * 16;
      byte ^= (row & 7) << 4;
      *(short8_t*)((char*)ldsK + byte) = v;
    }
#pragma unroll
    for (int it = 0; it < 4; ++it) {
      int c = it * 256 + tid;
      int d = c >> 3, cc = c & 7;
      short8_t v = *(const short8_t*)&vt[((size_t)h * HD + d) * S_LEN + kt + cc * 8];
      int byte = d * 128 + cc * 16;
      byte ^= (d & 7) << 4;
      *(short8_t*)((char*)ldsV + byte) = v;
    }
    __syncthreads();

    f32x4 sacc[4] = {};
#pragma unroll
    for (int n = 0; n < 4; ++n) {
#pragma unroll
      for (int kk = 0; kk < 4; ++kk) {
        int row = n * 16 + lr;
        int byte = row * 256 + (kk * 32 + lg * 8) * 2;
        byte ^= (row & 7) << 4;
        short8_t kf = *(const short8_t*)((const char*)ldsK + byte);
        sacc[n] = __builtin_amdgcn_mfma_f32_16x16x32_bf16(qf[kk], kf, sacc[n], 0, 0, 0);
      }
    }

    float sv[4][4];
#pragma unroll
    for (int n = 0; n < 4; ++n) {
      int key = kt + n * 16 + lr;
#pragma unroll
      for (int r = 0; r < 4; ++r) {
        float x = sacc[n][r] * ATTN_SCALE;
        sv[n][r] = (key >= rs[r] && key < re[r]) ? x : -1e30f;
      }
    }
    float alpha[4];
#pragma unroll
    for (int r = 0; r < 4; ++r) {
      float tm = fmaxf(fmaxf(sv[0][r], sv[1][r]), fmaxf(sv[2][r], sv[3][r]));
#pragma unroll
      for (int off = 1; off < 16; off <<= 1) tm = fmaxf(tm, __shfl_xor(tm, off));
      float mn = fmaxf(m[r], tm);
      alpha[r] = __expf(m[r] - mn);
      m[r] = mn;
      float ls = 0.f;
#pragma unroll
      for (int n = 0; n < 4; ++n) {
        float p = __expf(sv[n][r] - mn);
        sv[n][r] = p;
        ls += p;
      }
#pragma unroll
      for (int off = 1; off < 16; off <<= 1) ls += __shfl_xor(ls, off);
      lsum[r] = lsum[r] * alpha[r] + ls;
    }
#pragma unroll
    for (int n = 0; n < 8; ++n)
#pragma unroll
      for (int r = 0; r < 4; ++r) cacc[n][r] *= alpha[r];

#pragma unroll
    for (int n = 0; n < 4; ++n)
#pragma unroll
      for (int r = 0; r < 4; ++r) {
        int prow = lg * 4 + r;
        int pcol = n * 16 + lr;
        int byte = prow * 128 + pcol * 2;
        byte ^= (prow & 7) << 4;
        *(short*)((char*)ldsP + w * 2048 + byte) = f2bf(sv[n][r]);
      }
    __syncthreads();

#pragma unroll
    for (int kk = 0; kk < 2; ++kk) {
      int byteP = lr * 128 + (kk * 32 + lg * 8) * 2;
      byteP ^= (lr & 7) << 4;
      short8_t pf = *(const short8_t*)((const char*)ldsP + w * 2048 + byteP);
#pragma unroll
      for (int n = 0; n < 8; ++n) {
        int d = n * 16 + lr;
        int byteV = d * 128 + (kk * 32 + lg * 8) * 2;
        byteV ^= (d & 7) << 4;
        short8_t vf = *(const short8_t*)((const char*)ldsV + byteV);
        cacc[n] = __builtin_amdgcn_mfma_f32_16x16x32_bf16(pf, vf, cacc[n], 0, 0, 0);
      }
    }
  }

#pragma unroll
  for (int r = 0; r < 4; ++r) {
    float inv = 1.0f / lsum[r];
#pragma unroll
    for (int n = 0; n < 8; ++n) {
      float v = cacc[n][r] * inv;
      ctx[(size_t)rows[r] * EMB + h * HD + n * 16 + lr] = f2bf(v);
    }
  }
}

extern "C" void kernel_launch(void* const* d_in, const int* in_sizes, int n_in,
                              void* d_out, int out_size, void* d_ws, size_t ws_size,
                              hipStream_t stream) {
  const float* x      = (const float*)d_in[0];
  const int*   cu     = (const int*)d_in[1];
  const float* cosv   = (const float*)d_in[2];
  const float* sinv   = (const float*)d_in[3];
  const float* w_qkv  = (const float*)d_in[4];
  const float* b_qkv  = (const float*)d_in[5];
  const float* q_norm = (const float*)d_in[6];
  const float* k_norm = (const float*)d_in[7];
  const float* w_proj = (const float*)d_in[8];
  const float* b_proj = (const float*)d_in[9];
  const int nseg = in_sizes[1] - 1;

  char* ws = (char*)d_ws;
  short* xb     = (short*)(ws);                    //  6,291,456 B
  short* wqkvT  = (short*)(ws + 6291456);          // 14,155,776 B
  short* wprojT = (short*)(ws + 20447232);         //  4,718,592 B
  short* qkv16  = (short*)(ws + 25165824);         // 18,874,368 B (bf16 now)
  short* qb     = (short*)(ws + 44040192);         //  6,291,456 B
  short* kb     = (short*)(ws + 50331648);         //  6,291,456 B
  short* vt     = (short*)(ws + 56623104);         //  6,291,456 B
  short* ctxb   = (short*)(ws + 62914560);         //  6,291,456 B (end 69,206,016)

  k_cvt_bf16<<<(S_LEN * EMB) / 1024, 256, 0, stream>>>(x, xb, S_LEN * EMB);
  k_transpose_cvt<<<dim3(N3 / 32, EMB / 32), dim3(32, 8), 0, stream>>>(w_qkv, wqkvT, EMB, N3);
  k_transpose_cvt<<<dim3(EMB / 32, EMB / 32), dim3(32, 8), 0, stream>>>(w_proj, wprojT, EMB, EMB);
  k_gemm_v2<true><<<dim3(N3 / 128, S_LEN / 128), 256, 0, stream>>>(xb, wqkvT, b_qkv, qkv16, S_LEN, N3, EMB);
  k_post<<<dim3(NH, S_LEN / 64), 256, 0, stream>>>(qkv16, cosv, sinv, q_norm, k_norm, qb, kb, vt);
  k_attn<<<dim3(NH, S_LEN / 64), 256, 0, stream>>>(qb, kb, vt, cu, nseg, ctxb);
  k_gemm_v2<false><<<dim3(EMB / 128, S_LEN / 128), 256, 0, stream>>>(ctxb, wprojT, b_proj, (float*)d_out, S_LEN, EMB, EMB);
}